// Round 7
// baseline (312.674 us; speedup 1.0000x reference)
//
#include <hip/hip_runtime.h>
#include <hip/hip_bf16.h>

#define D 128
#define NN 40000
#define EE 640000
#define GG 8
#define NPG 5000
#define CSUB 16         // slots per (node, parity) sub-bucket; Poisson(8) each
#define OVCAP 4095

using short8 = __attribute__((ext_vector_type(8))) short;  // 8 bf16 (4 VGPRs)
using f32x4 = __attribute__((ext_vector_type(4))) float;   // MFMA accumulator

__device__ __forceinline__ float lrelu(float v) { return v >= 0.f ? v : 0.01f * v; }

__device__ __forceinline__ ushort f2bf(float f) {  // RNE fp32 -> bf16 bits
    union { float f; uint u; } c; c.f = f;
    return (ushort)((c.u + 0x7FFFu + ((c.u >> 16) & 1u)) >> 16);
}
__device__ __forceinline__ float bf2f_lo(uint u) { union { uint u; float f; } c; c.u = u << 16; return c.f; }
__device__ __forceinline__ float bf2f_hi(uint u) { union { uint u; float f; } c; c.u = u & 0xFFFF0000u; return c.f; }

// ---------------------------------------------------------------------------
// prep: blocks 0-3 transpose weights to bf16 W^T; blocks 4+ zero
// the contiguous {stats | deg2 | ov} region (replaces 3 hipMemsetAsync).
// ---------------------------------------------------------------------------
__global__ __launch_bounds__(256) void prep_k(const float* __restrict__ W1,
                                              const float* __restrict__ W2,
                                              const float* __restrict__ Wo,
                                              const float* __restrict__ Wn,
                                              short* __restrict__ WT,
                                              uint4* __restrict__ zbase, int zlen16) {
    const int b = blockIdx.x;
    if (b < 4) {
        const float* W = b == 0 ? W1 : b == 1 ? W2 : b == 2 ? Wo : Wn;
        short* T = WT + b * (D * D);
#pragma unroll 4
        for (int i = 0; i < 64; ++i) {
            int flat = threadIdx.x + i * 256;
            int k = flat >> 7, n = flat & 127;
            T[n * D + k] = (short)f2bf(W[flat]);
        }
    } else {
        int idx = (b - 4) * 256 + threadIdx.x;
        if (idx < zlen16) zbase[idx] = uint4{0, 0, 0, 0};
    }
}

// ---------------------------------------------------------------------------
// MFMA GEMM building blocks. As[64][136], Bs[128][136] bf16 in LDS.
// 4 waves: wave w owns rows [16w,16w+16), 8 n-tiles of 16 cols.
// ---------------------------------------------------------------------------
__device__ __forceinline__ void stage_B(const short* __restrict__ WT,
                                        short (*Bs)[136], int tid) {
    const uint4* bsrc = (const uint4*)WT;
#pragma unroll
    for (int i = 0; i < 8; ++i) {
        int idx = tid + i * 256;
        int flat = idx * 8;
        *(uint4*)&Bs[flat >> 7][flat & 127] = bsrc[idx];
    }
}

template <int ABF>
__device__ __forceinline__ void stage_A(const void* __restrict__ Av,
                                        short (*As)[136], int arow, int tid) {
    if constexpr (ABF) {  // bf16 source
        const uint4* asrc = (const uint4*)Av;
#pragma unroll
        for (int i = 0; i < 4; ++i) {
            int idx = tid + i * 256;
            int flat = idx * 8;
            *(uint4*)&As[flat >> 7][flat & 127] = asrc[(size_t)arow * 16 + idx];
        }
    } else {  // fp32 source, convert while staging
        const float4* A4 = (const float4*)Av;
#pragma unroll
        for (int i = 0; i < 8; ++i) {
            int idx = tid + i * 256;
            int row = idx >> 5, kq = idx & 31;
            float4 v = A4[(size_t)(arow + row) * 32 + kq];
            uint2 p;
            p.x = (uint)f2bf(v.x) | ((uint)f2bf(v.y) << 16);
            p.y = (uint)f2bf(v.z) | ((uint)f2bf(v.w) << 16);
            *(uint2*)&As[row][kq * 4] = p;
        }
    }
}

__device__ __forceinline__ void do_mfma(short (*As)[136], short (*Bs)[136],
                                        f32x4 (&acc)[8], int tid) {
    const int lane = tid & 63;
    const int m0 = (tid >> 6) * 16;
    const int lrow = lane & 15;
    const int kgrp = (lane >> 4) * 8;
#pragma unroll
    for (int ks = 0; ks < 4; ++ks) {
        const int kb = ks * 32 + kgrp;
        short8 a = *(const short8*)&As[m0 + lrow][kb];
#pragma unroll
        for (int nt = 0; nt < 8; ++nt) {
            short8 b = *(const short8*)&Bs[nt * 16 + lrow][kb];
            acc[nt] = __builtin_amdgcn_mfma_f32_16x16x32_bf16(a, b, acc[nt], 0, 0, 0);
        }
    }
}

// Fused MLP: h = leaky(x@W1) @ W2, t1 tile kept in LDS.
__global__ __launch_bounds__(256) void mlp_k(const float* __restrict__ x,
                                             const short* __restrict__ W1T,
                                             const short* __restrict__ W2T,
                                             ushort* __restrict__ h) {
    __shared__ short As[64][136];
    __shared__ short Bs[128][136];
    const int tid = threadIdx.x;
    const int arow = blockIdx.x * 64;
    f32x4 acc[8] = {};
    stage_A<0>(x, As, arow, tid);
    stage_B(W1T, Bs, tid);
    __syncthreads();
    do_mfma(As, Bs, acc, tid);
    __syncthreads();
    const int lane = tid & 63;
    const int c0 = lane & 15;
    const int r0 = (tid >> 6) * 16 + ((lane >> 4) << 2);
#pragma unroll
    for (int nt = 0; nt < 8; ++nt)
#pragma unroll
        for (int r = 0; r < 4; ++r)
            As[r0 + r][nt * 16 + c0] = (short)f2bf(lrelu(acc[nt][r]));
    stage_B(W2T, Bs, tid);
#pragma unroll
    for (int nt = 0; nt < 8; ++nt) acc[nt] = f32x4{0.f, 0.f, 0.f, 0.f};
    __syncthreads();
    do_mfma(As, Bs, acc, tid);
#pragma unroll
    for (int nt = 0; nt < 8; ++nt)
#pragma unroll
        for (int r = 0; r < 4; ++r)
            h[(size_t)(arow + r0 + r) * D + nt * 16 + c0] = f2bf(acc[nt][r]);
}

// ---------------------------------------------------------------------------
// CSR build, 2-way-split degree counters: deg2[dst*2 + (e&1)].
// 2x cache lines for the atomic histogram -> half the per-line RMW queue.
// ---------------------------------------------------------------------------
__global__ __launch_bounds__(256) void fill_k(const int* __restrict__ ei,
                                              const float* __restrict__ w,
                                              int* __restrict__ deg2,
                                              int2* __restrict__ csr,
                                              int* __restrict__ ov) {
    const int t = blockIdx.x * 256 + threadIdx.x;   // EE/2 threads
    const int e0 = t * 2;
    const int2 dst = *(const int2*)&ei[e0];
    const int2 src = *(const int2*)&ei[EE + e0];
    const float2 wv = *(const float2*)&w[e0];
    const int p0 = atomicAdd(&deg2[dst.x * 2], 1);       // e0 even
    const int p1 = atomicAdd(&deg2[dst.y * 2 + 1], 1);   // e0+1 odd
    if (p0 < CSUB) csr[(size_t)dst.x * 32 + p0] = make_int2(src.x, __float_as_int(wv.x));
    else { int oi = atomicAdd(&ov[0], 1); if (oi < OVCAP) ov[1 + oi] = e0; }
    if (p1 < CSUB) csr[(size_t)dst.y * 32 + CSUB + p1] = make_int2(src.y, __float_as_int(wv.y));
    else { int oi = atomicAdd(&ov[0], 1); if (oi < OVCAP) ov[1 + oi] = e0 + 1; }
}

// gather: 32-lane half-wave per node; both sub-buckets + inline overflow scan.
// Full fp32 sum -> leaky -> ONE bf16 rounding -> store xn_act (bf16).
__global__ __launch_bounds__(256) void gather_k(const ushort* __restrict__ h,
                                                const int* __restrict__ deg2,
                                                const int2* __restrict__ csr,
                                                const int* __restrict__ ei,
                                                const float* __restrict__ w,
                                                const int* __restrict__ ov,
                                                ushort* __restrict__ xnact) {
    const int n = blockIdx.x * 8 + (threadIdx.x >> 5);
    const int lane = threadIdx.x & 31;
    const int2 dd = *(const int2*)&deg2[2 * n];
    const int c0 = min(dd.x, CSUB), c1 = min(dd.y, CSUB);
    const int total = c0 + c1;
    const int shift = CSUB - c0;   // map j -> slot (sub0: [0,c0), sub1: [16,16+c1))
    const int2* row = csr + (size_t)n * 32;
    float4 acc = {0.f, 0.f, 0.f, 0.f};
    int j = 0;
    for (; j + 8 <= total; j += 8) {
        int2 p[8]; uint2 v[8];
#pragma unroll
        for (int t = 0; t < 8; ++t) { int jj = j + t; p[t] = row[jj < c0 ? jj : jj + shift]; }
#pragma unroll
        for (int t = 0; t < 8; ++t) v[t] = *((const uint2*)(h + (size_t)p[t].x * D) + lane);
#pragma unroll
        for (int t = 0; t < 8; ++t) {
            const float wv = __int_as_float(p[t].y);
            acc.x += wv * bf2f_lo(v[t].x);
            acc.y += wv * bf2f_hi(v[t].x);
            acc.z += wv * bf2f_lo(v[t].y);
            acc.w += wv * bf2f_hi(v[t].y);
        }
    }
    if (j + 4 <= total) {
        int2 p[4]; uint2 v[4];
#pragma unroll
        for (int t = 0; t < 4; ++t) { int jj = j + t; p[t] = row[jj < c0 ? jj : jj + shift]; }
#pragma unroll
        for (int t = 0; t < 4; ++t) v[t] = *((const uint2*)(h + (size_t)p[t].x * D) + lane);
#pragma unroll
        for (int t = 0; t < 4; ++t) {
            const float wv = __int_as_float(p[t].y);
            acc.x += wv * bf2f_lo(v[t].x);
            acc.y += wv * bf2f_hi(v[t].x);
            acc.z += wv * bf2f_lo(v[t].y);
            acc.w += wv * bf2f_hi(v[t].y);
        }
        j += 4;
    }
    for (; j < total; ++j) {
        int2 p = row[j < c0 ? j : j + shift];
        const uint2 v = *((const uint2*)(h + (size_t)p.x * D) + lane);
        const float wv = __int_as_float(p.y);
        acc.x += wv * bf2f_lo(v.x);
        acc.y += wv * bf2f_hi(v.x);
        acc.z += wv * bf2f_lo(v.y);
        acc.w += wv * bf2f_hi(v.y);
    }
    if (dd.x > CSUB || dd.y > CSUB) {  // rare: scan overflow list for this node
        const int cnt = min(ov[0], OVCAP);
        for (int i = 0; i < cnt; ++i) {
            const int e = ov[1 + i];
            if (ei[e] == n) {
                const float wv = w[e];
                const uint2 v = *((const uint2*)(h + (size_t)ei[EE + e] * D) + lane);
                acc.x += wv * bf2f_lo(v.x);
                acc.y += wv * bf2f_hi(v.x);
                acc.z += wv * bf2f_lo(v.y);
                acc.w += wv * bf2f_hi(v.y);
            }
        }
    }
    uint2 st;
    st.x = (uint)f2bf(lrelu(acc.x)) | ((uint)f2bf(lrelu(acc.y)) << 16);
    st.y = (uint)f2bf(lrelu(acc.z)) | ((uint)f2bf(lrelu(acc.w)) << 16);
    *((uint2*)(xnact + (size_t)n * D) + lane) = st;
}

// ---------------------------------------------------------------------------
// out = h@Wo + xn_act@Wn, with fused GraphNorm stats (sum, sumsq) epilogue.
// Stats go to 8 blockIdx-replicated buffers (atomic line-contention control).
// ---------------------------------------------------------------------------
__global__ __launch_bounds__(256) void mmstats_k(const ushort* __restrict__ h,
                                                 const short* __restrict__ WoT,
                                                 const ushort* __restrict__ xa,
                                                 const short* __restrict__ WnT,
                                                 float* __restrict__ out,
                                                 float* __restrict__ stats) {
    __shared__ short As[64][136];
    __shared__ short Bs[128][136];
    const int tid = threadIdx.x;
    const int arow = blockIdx.x * 64;
    f32x4 acc[8] = {};
    stage_A<1>(h, As, arow, tid);
    stage_B(WoT, Bs, tid);
    __syncthreads();
    do_mfma(As, Bs, acc, tid);
    __syncthreads();
    stage_A<1>(xa, As, arow, tid);
    stage_B(WnT, Bs, tid);
    __syncthreads();
    do_mfma(As, Bs, acc, tid);
    __syncthreads();                       // As dead -> reuse as ls_s/ls_q
    float* ls_s = (float*)As;              // [16][132]
    float* ls_q = ls_s + 16 * 132;         // 2*16*132*4 = 16896 B <= sizeof(As)
    const int lane = tid & 63;
    const int c0 = lane & 15;
    const int r0 = (tid >> 6) * 16 + ((lane >> 4) << 2);
    const int li = (tid >> 6) * 4 + (lane >> 4);   // row-group id 0..15 (rows 4li..4li+3)
#pragma unroll
    for (int nt = 0; nt < 8; ++nt) {
        float s = 0.f, q = 0.f;
#pragma unroll
        for (int r = 0; r < 4; ++r) {
            const float v = acc[nt][r];
            out[(size_t)(arow + r0 + r) * D + nt * 16 + c0] = v;
            s += v; q += v * v;
        }
        ls_s[li * 132 + nt * 16 + c0] = s;
        ls_q[li * 132 + nt * 16 + c0] = q;
    }
    __syncthreads();
    if (tid < 128) {   // one thread per column
        const int g0 = arow / NPG;
        const int gsplit = (g0 + 1) * NPG - arow;  // rows in graph g0; %4==0 always
        float s0 = 0.f, q0 = 0.f, s1 = 0.f, q1 = 0.f;
#pragma unroll
        for (int i = 0; i < 16; ++i) {
            const float sv = ls_s[i * 132 + tid];
            const float qv = ls_q[i * 132 + tid];
            if (i * 4 >= gsplit) { s1 += sv; q1 += qv; }
            else { s0 += sv; q0 += qv; }
        }
        const int rep = blockIdx.x & 7;
        float* S = &stats[((size_t)(rep * 2 + 0) * GG + g0) * D + tid];
        float* Q = &stats[((size_t)(rep * 2 + 1) * GG + g0) * D + tid];
        atomicAdd(S, s0);
        atomicAdd(Q, q0);
        if (gsplit < 64) { atomicAdd(S + D, s1); atomicAdd(Q + D, q1); }
    }
}

// norm: reduce the 8 stats replicas inline, normalize, scale, shift.
__global__ __launch_bounds__(256) void norm_k(float* __restrict__ out,
                                              const float* __restrict__ stats,
                                              const float* __restrict__ gamma,
                                              const float* __restrict__ beta) {
    const int i4 = blockIdx.x * 256 + threadIdx.x;  // over NN*D/4
    const int row = i4 >> 5;
    const int g = row / NPG;
    const int d0 = (i4 & 31) * 4;
    float4 v = *((float4*)out + i4);
    float4 s4 = {0.f, 0.f, 0.f, 0.f}, q4 = {0.f, 0.f, 0.f, 0.f};
#pragma unroll
    for (int rep = 0; rep < 8; ++rep) {
        const float4 sr = *(const float4*)&stats[((size_t)(rep * 2 + 0) * GG + g) * D + d0];
        const float4 qr = *(const float4*)&stats[((size_t)(rep * 2 + 1) * GG + g) * D + d0];
        s4.x += sr.x; s4.y += sr.y; s4.z += sr.z; s4.w += sr.w;
        q4.x += qr.x; q4.y += qr.y; q4.z += qr.z; q4.w += qr.w;
    }
    const float4 g4 = *(const float4*)&gamma[d0];
    const float4 b4 = *(const float4*)&beta[d0];
    const float inv = 1.f / (float)NPG;
    const float invm1 = 1.f / (float)(NPG - 1);
    float mu, var, sg;
    mu = s4.x * inv; var = (q4.x - s4.x * mu) * invm1; sg = sqrtf(fmaxf(var, 0.f));
    v.x = (v.x - mu) / (sg + 1e-6f) * g4.x + b4.x;
    mu = s4.y * inv; var = (q4.y - s4.y * mu) * invm1; sg = sqrtf(fmaxf(var, 0.f));
    v.y = (v.y - mu) / (sg + 1e-6f) * g4.y + b4.y;
    mu = s4.z * inv; var = (q4.z - s4.z * mu) * invm1; sg = sqrtf(fmaxf(var, 0.f));
    v.z = (v.z - mu) / (sg + 1e-6f) * g4.z + b4.z;
    mu = s4.w * inv; var = (q4.w - s4.w * mu) * invm1; sg = sqrtf(fmaxf(var, 0.f));
    v.w = (v.w - mu) / (sg + 1e-6f) * g4.w + b4.w;
    *((float4*)out + i4) = v;
}

extern "C" void kernel_launch(void* const* d_in, const int* in_sizes, int n_in,
                              void* d_out, int out_size, void* d_ws, size_t ws_size,
                              hipStream_t stream) {
    const float* x = (const float*)d_in[0];
    const int* ei = (const int*)d_in[1];
    const float* w = (const float*)d_in[2];
    const float* W1 = (const float*)d_in[5];
    const float* W2 = (const float*)d_in[6];
    const float* Wo = (const float*)d_in[7];
    const float* Wn = (const float*)d_in[8];
    const float* gamma = (const float*)d_in[9];
    const float* beta = (const float*)d_in[10];
    float* out = (float*)d_out;

    char* ws = (char*)d_ws;
    const size_t BF16MAT = (size_t)NN * D * 2;        // 10,240,000
    size_t off = 0;
    ushort* h = (ushort*)(ws + off);      off += BF16MAT;
    ushort* xnact = (ushort*)(ws + off);  off += BF16MAT;
    const size_t ZOFF = off;                                   // zero region start
    float* stats = (float*)(ws + off);    off += 8 * 2 * GG * D * 4;     // 65,536
    int* deg2 = (int*)(ws + off);         off += (size_t)NN * 2 * 4;     // 320,000
    int* ov = (int*)(ws + off);           off += (1 + OVCAP) * 4;        // 16,384
    const int ZLEN16 = (int)((off - ZOFF) / 16);               // 25,120 uint4s
    short* WT = (short*)(ws + off);       off += 4 * (size_t)D * D * 2;  // 131,072
    int2* csr = (int2*)(ws + off);        // NN*32*8 = 10,240,000; total ~31.3 MB

    prep_k<<<4 + (ZLEN16 + 255) / 256, 256, 0, stream>>>(W1, W2, Wo, Wn, WT,
                                                         (uint4*)(ws + ZOFF), ZLEN16);
    mlp_k<<<NN / 64, 256, 0, stream>>>(x, WT, WT + D * D, h);
    fill_k<<<EE / (256 * 2), 256, 0, stream>>>(ei, w, deg2, csr, ov);
    gather_k<<<NN / 8, 256, 0, stream>>>(h, deg2, csr, ei, w, ov, xnact);
    mmstats_k<<<NN / 64, 256, 0, stream>>>(h, WT + 2 * D * D, xnact, WT + 3 * D * D, out, stats);
    norm_k<<<(NN * D / 4) / 256, 256, 0, stream>>>(out, stats, gamma, beta);
}

// Round 8
// 198.827 us; speedup vs baseline: 1.5726x; 1.5726x over previous
//
#include <hip/hip_runtime.h>
#include <hip/hip_bf16.h>

#define D 128
#define NN 40000
#define EE 640000
#define GG 8
#define NPG 5000
#define CSUB 16         // slots per (node, e&3) sub-bucket; load ~ Poisson(4)
#define OVCAP 4095

using short8 = __attribute__((ext_vector_type(8))) short;  // 8 bf16 (4 VGPRs)
using f32x4 = __attribute__((ext_vector_type(4))) float;   // MFMA accumulator

__device__ __forceinline__ float lrelu(float v) { return v >= 0.f ? v : 0.01f * v; }

__device__ __forceinline__ ushort f2bf(float f) {  // RNE fp32 -> bf16 bits
    union { float f; uint u; } c; c.f = f;
    return (ushort)((c.u + 0x7FFFu + ((c.u >> 16) & 1u)) >> 16);
}
__device__ __forceinline__ float bf2f_lo(uint u) { union { uint u; float f; } c; c.u = u << 16; return c.f; }
__device__ __forceinline__ float bf2f_hi(uint u) { union { uint u; float f; } c; c.u = u & 0xFFFF0000u; return c.f; }

// ---------------------------------------------------------------------------
// prep: blocks 0-3 transpose weights to bf16 W^T; blocks 4+ zero {stats|deg4|ov}.
// ---------------------------------------------------------------------------
__global__ __launch_bounds__(256) void prep_k(const float* __restrict__ W1,
                                              const float* __restrict__ W2,
                                              const float* __restrict__ Wo,
                                              const float* __restrict__ Wn,
                                              short* __restrict__ WT,
                                              uint4* __restrict__ zbase, int zlen16) {
    const int b = blockIdx.x;
    if (b < 4) {
        const float* W = b == 0 ? W1 : b == 1 ? W2 : b == 2 ? Wo : Wn;
        short* T = WT + b * (D * D);
#pragma unroll 4
        for (int i = 0; i < 64; ++i) {
            int flat = threadIdx.x + i * 256;
            int k = flat >> 7, n = flat & 127;
            T[n * D + k] = (short)f2bf(W[flat]);
        }
    } else {
        int idx = (b - 4) * 256 + threadIdx.x;
        if (idx < zlen16) zbase[idx] = uint4{0, 0, 0, 0};
    }
}

// ---------------------------------------------------------------------------
// MFMA GEMM building blocks. As[64][136], Bs[128][136] bf16 in LDS.
// ---------------------------------------------------------------------------
__device__ __forceinline__ void stage_B(const short* __restrict__ WT,
                                        short (*Bs)[136], int tid) {
    const uint4* bsrc = (const uint4*)WT;
#pragma unroll
    for (int i = 0; i < 8; ++i) {
        int idx = tid + i * 256;
        int flat = idx * 8;
        *(uint4*)&Bs[flat >> 7][flat & 127] = bsrc[idx];
    }
}

template <int ABF>
__device__ __forceinline__ void stage_A(const void* __restrict__ Av,
                                        short (*As)[136], int arow, int tid) {
    if constexpr (ABF) {  // bf16 source
        const uint4* asrc = (const uint4*)Av;
#pragma unroll
        for (int i = 0; i < 4; ++i) {
            int idx = tid + i * 256;
            int flat = idx * 8;
            *(uint4*)&As[flat >> 7][flat & 127] = asrc[(size_t)arow * 16 + idx];
        }
    } else {  // fp32 source, convert while staging
        const float4* A4 = (const float4*)Av;
#pragma unroll
        for (int i = 0; i < 8; ++i) {
            int idx = tid + i * 256;
            int row = idx >> 5, kq = idx & 31;
            float4 v = A4[(size_t)(arow + row) * 32 + kq];
            uint2 p;
            p.x = (uint)f2bf(v.x) | ((uint)f2bf(v.y) << 16);
            p.y = (uint)f2bf(v.z) | ((uint)f2bf(v.w) << 16);
            *(uint2*)&As[row][kq * 4] = p;
        }
    }
}

__device__ __forceinline__ void do_mfma(short (*As)[136], short (*Bs)[136],
                                        f32x4 (&acc)[8], int tid) {
    const int lane = tid & 63;
    const int m0 = (tid >> 6) * 16;
    const int lrow = lane & 15;
    const int kgrp = (lane >> 4) * 8;
#pragma unroll
    for (int ks = 0; ks < 4; ++ks) {
        const int kb = ks * 32 + kgrp;
        short8 a = *(const short8*)&As[m0 + lrow][kb];
#pragma unroll
        for (int nt = 0; nt < 8; ++nt) {
            short8 b = *(const short8*)&Bs[nt * 16 + lrow][kb];
            acc[nt] = __builtin_amdgcn_mfma_f32_16x16x32_bf16(a, b, acc[nt], 0, 0, 0);
        }
    }
}

// Fused MLP: h = leaky(x@W1) @ W2, t1 tile kept in LDS.
__global__ __launch_bounds__(256) void mlp_k(const float* __restrict__ x,
                                             const short* __restrict__ W1T,
                                             const short* __restrict__ W2T,
                                             ushort* __restrict__ h) {
    __shared__ short As[64][136];
    __shared__ short Bs[128][136];
    const int tid = threadIdx.x;
    const int arow = blockIdx.x * 64;
    f32x4 acc[8] = {};
    stage_A<0>(x, As, arow, tid);
    stage_B(W1T, Bs, tid);
    __syncthreads();
    do_mfma(As, Bs, acc, tid);
    __syncthreads();
    const int lane = tid & 63;
    const int c0 = lane & 15;
    const int r0 = (tid >> 6) * 16 + ((lane >> 4) << 2);
#pragma unroll
    for (int nt = 0; nt < 8; ++nt)
#pragma unroll
        for (int r = 0; r < 4; ++r)
            As[r0 + r][nt * 16 + c0] = (short)f2bf(lrelu(acc[nt][r]));
    stage_B(W2T, Bs, tid);
#pragma unroll
    for (int nt = 0; nt < 8; ++nt) acc[nt] = f32x4{0.f, 0.f, 0.f, 0.f};
    __syncthreads();
    do_mfma(As, Bs, acc, tid);
#pragma unroll
    for (int nt = 0; nt < 8; ++nt)
#pragma unroll
        for (int r = 0; r < 4; ++r)
            h[(size_t)(arow + r0 + r) * D + nt * 16 + c0] = f2bf(acc[nt][r]);
}

// ---------------------------------------------------------------------------
// CSR build: 4 edges/thread, 4-way split counters deg4[par*NN + dst]
// (par = e&3) -> 4 SEPARATE arrays => 4x cache lines, 64 RMW/line.
// ---------------------------------------------------------------------------
__global__ __launch_bounds__(256) void fill_k(const int* __restrict__ ei,
                                              const float* __restrict__ w,
                                              int* __restrict__ deg4,
                                              int2* __restrict__ csr,
                                              int* __restrict__ ov) {
    const int t = blockIdx.x * 256 + threadIdx.x;   // EE/4 threads
    const int e0 = t * 4;
    const int4 dst = *(const int4*)&ei[e0];
    const int4 src = *(const int4*)&ei[EE + e0];
    const float4 wv = *(const float4*)&w[e0];
    const int ds[4] = {dst.x, dst.y, dst.z, dst.w};
    const int sr[4] = {src.x, src.y, src.z, src.w};
    const float wf[4] = {wv.x, wv.y, wv.z, wv.w};
    int pos[4];
#pragma unroll
    for (int k = 0; k < 4; ++k) pos[k] = atomicAdd(&deg4[k * NN + ds[k]], 1);
#pragma unroll
    for (int k = 0; k < 4; ++k) {
        if (pos[k] < CSUB) {
            csr[(size_t)ds[k] * 64 + k * CSUB + pos[k]] = make_int2(sr[k], __float_as_int(wf[k]));
        } else {
            const int oi = atomicAdd(&ov[0], 1);
            if (oi < OVCAP) ov[1 + oi] = e0 + k;
        }
    }
}

// gather: quarter-wave (16 lanes x uint4 = 256B/row) per node, 16 nodes/block,
// 8-deep batched loads. Flattened 4-bucket index map. fp32 sum -> leaky ->
// one bf16 rounding -> xnact. Overflow scan never fires (P ~ 3e-7/bucket).
__global__ __launch_bounds__(256) void gather_k(const ushort* __restrict__ h,
                                                const int* __restrict__ deg4,
                                                const int2* __restrict__ csr,
                                                const int* __restrict__ ei,
                                                const float* __restrict__ w,
                                                const int* __restrict__ ov,
                                                ushort* __restrict__ xnact) {
    const int n = blockIdx.x * 16 + (threadIdx.x >> 4);
    const int lane = threadIdx.x & 15;
    const int d0 = deg4[0 * NN + n], d1 = deg4[1 * NN + n];
    const int d2 = deg4[2 * NN + n], d3 = deg4[3 * NN + n];
    const int c0 = min(d0, CSUB), c1 = min(d1, CSUB);
    const int c2 = min(d2, CSUB), c3 = min(d3, CSUB);
    const int t0 = c0, t1 = t0 + c1, t2 = t1 + c2;
    const int total = t2 + c3;
    const int2* row = csr + (size_t)n * 64;
    float acc[8] = {};
    int j = 0;
    for (; j + 8 <= total; j += 8) {
        int2 p[8]; uint4 v[8];
#pragma unroll
        for (int t = 0; t < 8; ++t) {
            const int jj = j + t;
            const int s = jj < t0 ? jj
                        : jj < t1 ? jj - t0 + CSUB
                        : jj < t2 ? jj - t1 + 2 * CSUB
                                  : jj - t2 + 3 * CSUB;
            p[t] = row[s];
        }
#pragma unroll
        for (int t = 0; t < 8; ++t) v[t] = *((const uint4*)(h + (size_t)p[t].x * D) + lane);
#pragma unroll
        for (int t = 0; t < 8; ++t) {
            const float wv = __int_as_float(p[t].y);
            acc[0] += wv * bf2f_lo(v[t].x); acc[1] += wv * bf2f_hi(v[t].x);
            acc[2] += wv * bf2f_lo(v[t].y); acc[3] += wv * bf2f_hi(v[t].y);
            acc[4] += wv * bf2f_lo(v[t].z); acc[5] += wv * bf2f_hi(v[t].z);
            acc[6] += wv * bf2f_lo(v[t].w); acc[7] += wv * bf2f_hi(v[t].w);
        }
    }
    if (j + 4 <= total) {
        int2 p[4]; uint4 v[4];
#pragma unroll
        for (int t = 0; t < 4; ++t) {
            const int jj = j + t;
            const int s = jj < t0 ? jj
                        : jj < t1 ? jj - t0 + CSUB
                        : jj < t2 ? jj - t1 + 2 * CSUB
                                  : jj - t2 + 3 * CSUB;
            p[t] = row[s];
        }
#pragma unroll
        for (int t = 0; t < 4; ++t) v[t] = *((const uint4*)(h + (size_t)p[t].x * D) + lane);
#pragma unroll
        for (int t = 0; t < 4; ++t) {
            const float wv = __int_as_float(p[t].y);
            acc[0] += wv * bf2f_lo(v[t].x); acc[1] += wv * bf2f_hi(v[t].x);
            acc[2] += wv * bf2f_lo(v[t].y); acc[3] += wv * bf2f_hi(v[t].y);
            acc[4] += wv * bf2f_lo(v[t].z); acc[5] += wv * bf2f_hi(v[t].z);
            acc[6] += wv * bf2f_lo(v[t].w); acc[7] += wv * bf2f_hi(v[t].w);
        }
        j += 4;
    }
    for (; j < total; ++j) {
        const int s = j < t0 ? j
                    : j < t1 ? j - t0 + CSUB
                    : j < t2 ? j - t1 + 2 * CSUB
                             : j - t2 + 3 * CSUB;
        const int2 p = row[s];
        const uint4 v = *((const uint4*)(h + (size_t)p.x * D) + lane);
        const float wv = __int_as_float(p.y);
        acc[0] += wv * bf2f_lo(v.x); acc[1] += wv * bf2f_hi(v.x);
        acc[2] += wv * bf2f_lo(v.y); acc[3] += wv * bf2f_hi(v.y);
        acc[4] += wv * bf2f_lo(v.z); acc[5] += wv * bf2f_hi(v.z);
        acc[6] += wv * bf2f_lo(v.w); acc[7] += wv * bf2f_hi(v.w);
    }
    if (d0 > CSUB || d1 > CSUB || d2 > CSUB || d3 > CSUB) {  // ~never
        const int cnt = min(ov[0], OVCAP);
        for (int i = 0; i < cnt; ++i) {
            const int e = ov[1 + i];
            if (ei[e] == n) {
                const float wv = w[e];
                const uint4 v = *((const uint4*)(h + (size_t)ei[EE + e] * D) + lane);
                acc[0] += wv * bf2f_lo(v.x); acc[1] += wv * bf2f_hi(v.x);
                acc[2] += wv * bf2f_lo(v.y); acc[3] += wv * bf2f_hi(v.y);
                acc[4] += wv * bf2f_lo(v.z); acc[5] += wv * bf2f_hi(v.z);
                acc[6] += wv * bf2f_lo(v.w); acc[7] += wv * bf2f_hi(v.w);
            }
        }
    }
    uint4 st;
    st.x = (uint)f2bf(lrelu(acc[0])) | ((uint)f2bf(lrelu(acc[1])) << 16);
    st.y = (uint)f2bf(lrelu(acc[2])) | ((uint)f2bf(lrelu(acc[3])) << 16);
    st.z = (uint)f2bf(lrelu(acc[4])) | ((uint)f2bf(lrelu(acc[5])) << 16);
    st.w = (uint)f2bf(lrelu(acc[6])) | ((uint)f2bf(lrelu(acc[7])) << 16);
    *((uint4*)(xnact + (size_t)n * D) + lane) = st;
}

// ---------------------------------------------------------------------------
// out = h@Wo + xn_act@Wn, fused GraphNorm stats epilogue (8 replica buffers).
// ---------------------------------------------------------------------------
__global__ __launch_bounds__(256) void mmstats_k(const ushort* __restrict__ h,
                                                 const short* __restrict__ WoT,
                                                 const ushort* __restrict__ xa,
                                                 const short* __restrict__ WnT,
                                                 float* __restrict__ out,
                                                 float* __restrict__ stats) {
    __shared__ short As[64][136];
    __shared__ short Bs[128][136];
    const int tid = threadIdx.x;
    const int arow = blockIdx.x * 64;
    f32x4 acc[8] = {};
    stage_A<1>(h, As, arow, tid);
    stage_B(WoT, Bs, tid);
    __syncthreads();
    do_mfma(As, Bs, acc, tid);
    __syncthreads();
    stage_A<1>(xa, As, arow, tid);
    stage_B(WnT, Bs, tid);
    __syncthreads();
    do_mfma(As, Bs, acc, tid);
    __syncthreads();                       // As dead -> reuse as ls_s/ls_q
    float* ls_s = (float*)As;              // [16][132]
    float* ls_q = ls_s + 16 * 132;         // 16896 B <= sizeof(As)
    const int lane = tid & 63;
    const int c0 = lane & 15;
    const int r0 = (tid >> 6) * 16 + ((lane >> 4) << 2);
    const int li = (tid >> 6) * 4 + (lane >> 4);
#pragma unroll
    for (int nt = 0; nt < 8; ++nt) {
        float s = 0.f, q = 0.f;
#pragma unroll
        for (int r = 0; r < 4; ++r) {
            const float v = acc[nt][r];
            out[(size_t)(arow + r0 + r) * D + nt * 16 + c0] = v;
            s += v; q += v * v;
        }
        ls_s[li * 132 + nt * 16 + c0] = s;
        ls_q[li * 132 + nt * 16 + c0] = q;
    }
    __syncthreads();
    if (tid < 128) {
        const int g0 = arow / NPG;
        const int gsplit = (g0 + 1) * NPG - arow;
        float s0 = 0.f, q0 = 0.f, s1 = 0.f, q1 = 0.f;
#pragma unroll
        for (int i = 0; i < 16; ++i) {
            const float sv = ls_s[i * 132 + tid];
            const float qv = ls_q[i * 132 + tid];
            if (i * 4 >= gsplit) { s1 += sv; q1 += qv; }
            else { s0 += sv; q0 += qv; }
        }
        const int rep = blockIdx.x & 7;
        float* S = &stats[((size_t)(rep * 2 + 0) * GG + g0) * D + tid];
        float* Q = &stats[((size_t)(rep * 2 + 1) * GG + g0) * D + tid];
        atomicAdd(S, s0);
        atomicAdd(Q, q0);
        if (gsplit < 64) { atomicAdd(S + D, s1); atomicAdd(Q + D, q1); }
    }
}

// norm: reduce 8 stats replicas inline, normalize, scale, shift.
__global__ __launch_bounds__(256) void norm_k(float* __restrict__ out,
                                              const float* __restrict__ stats,
                                              const float* __restrict__ gamma,
                                              const float* __restrict__ beta) {
    const int i4 = blockIdx.x * 256 + threadIdx.x;
    const int row = i4 >> 5;
    const int g = row / NPG;
    const int d0 = (i4 & 31) * 4;
    float4 v = *((float4*)out + i4);
    float4 s4 = {0.f, 0.f, 0.f, 0.f}, q4 = {0.f, 0.f, 0.f, 0.f};
#pragma unroll
    for (int rep = 0; rep < 8; ++rep) {
        const float4 sr = *(const float4*)&stats[((size_t)(rep * 2 + 0) * GG + g) * D + d0];
        const float4 qr = *(const float4*)&stats[((size_t)(rep * 2 + 1) * GG + g) * D + d0];
        s4.x += sr.x; s4.y += sr.y; s4.z += sr.z; s4.w += sr.w;
        q4.x += qr.x; q4.y += qr.y; q4.z += qr.z; q4.w += qr.w;
    }
    const float4 g4 = *(const float4*)&gamma[d0];
    const float4 b4 = *(const float4*)&beta[d0];
    const float inv = 1.f / (float)NPG;
    const float invm1 = 1.f / (float)(NPG - 1);
    float mu, var, sg;
    mu = s4.x * inv; var = (q4.x - s4.x * mu) * invm1; sg = sqrtf(fmaxf(var, 0.f));
    v.x = (v.x - mu) / (sg + 1e-6f) * g4.x + b4.x;
    mu = s4.y * inv; var = (q4.y - s4.y * mu) * invm1; sg = sqrtf(fmaxf(var, 0.f));
    v.y = (v.y - mu) / (sg + 1e-6f) * g4.y + b4.y;
    mu = s4.z * inv; var = (q4.z - s4.z * mu) * invm1; sg = sqrtf(fmaxf(var, 0.f));
    v.z = (v.z - mu) / (sg + 1e-6f) * g4.z + b4.z;
    mu = s4.w * inv; var = (q4.w - s4.w * mu) * invm1; sg = sqrtf(fmaxf(var, 0.f));
    v.w = (v.w - mu) / (sg + 1e-6f) * g4.w + b4.w;
    *((float4*)out + i4) = v;
}

extern "C" void kernel_launch(void* const* d_in, const int* in_sizes, int n_in,
                              void* d_out, int out_size, void* d_ws, size_t ws_size,
                              hipStream_t stream) {
    const float* x = (const float*)d_in[0];
    const int* ei = (const int*)d_in[1];
    const float* w = (const float*)d_in[2];
    const float* W1 = (const float*)d_in[5];
    const float* W2 = (const float*)d_in[6];
    const float* Wo = (const float*)d_in[7];
    const float* Wn = (const float*)d_in[8];
    const float* gamma = (const float*)d_in[9];
    const float* beta = (const float*)d_in[10];
    float* out = (float*)d_out;

    char* ws = (char*)d_ws;
    const size_t BF16MAT = (size_t)NN * D * 2;        // 10,240,000
    size_t off = 0;
    ushort* h = (ushort*)(ws + off);      off += BF16MAT;
    ushort* xnact = (ushort*)(ws + off);  off += BF16MAT;
    const size_t ZOFF = off;                                   // zero region start
    float* stats = (float*)(ws + off);    off += 8 * 2 * GG * D * 4;     // 65,536
    int* deg4 = (int*)(ws + off);         off += (size_t)NN * 4 * 4;     // 640,000
    int* ov = (int*)(ws + off);           off += (1 + OVCAP) * 4;        // 16,384
    const int ZLEN16 = (int)((off - ZOFF) / 16);
    short* WT = (short*)(ws + off);       off += 4 * (size_t)D * D * 2;  // 131,072
    int2* csr = (int2*)(ws + off);        // NN*64*8 = 20,480,000; total ~42 MB

    prep_k<<<4 + (ZLEN16 + 255) / 256, 256, 0, stream>>>(W1, W2, Wo, Wn, WT,
                                                         (uint4*)(ws + ZOFF), ZLEN16);
    mlp_k<<<NN / 64, 256, 0, stream>>>(x, WT, WT + D * D, h);
    fill_k<<<EE / (256 * 4), 256, 0, stream>>>(ei, w, deg4, csr, ov);
    gather_k<<<NN / 16, 256, 0, stream>>>(h, deg4, csr, ei, w, ov, xnact);
    mmstats_k<<<NN / 64, 256, 0, stream>>>(h, WT + 2 * D * D, xnact, WT + 3 * D * D, out, stats);
    norm_k<<<(NN * D / 4) / 256, 256, 0, stream>>>(out, stats, gamma, beta);
}